// Round 11
// baseline (231.515 us; speedup 1.0000x reference)
//
#include <hip/hip_runtime.h>

#define S_LEN 2048

typedef float f32x4 __attribute__((ext_vector_type(4)));

__device__ __forceinline__ float rlane(float v, int l) {
    return __int_as_float(__builtin_amdgcn_readlane(__float_as_int(v), l));
}
__device__ __forceinline__ float rfl(float v) {
    return __int_as_float(__builtin_amdgcn_readfirstlane(__float_as_int(v)));
}

template<int CTRL, int RM>
__device__ __forceinline__ float dpp_add(float v) {
    int t = __builtin_amdgcn_update_dpp(0, __float_as_int(v), CTRL, RM, 0xF, true);
    return v + __int_as_float(t);
}
// sum across 64 lanes -> uniform scalar, VALU-only.
__device__ __forceinline__ float wave_sum(float v) {
    v = dpp_add<0x111, 0xF>(v);
    v = dpp_add<0x112, 0xF>(v);
    v = dpp_add<0x114, 0xF>(v);
    v = dpp_add<0x118, 0xF>(v);
    v = dpp_add<0x142, 0xA>(v);
    v = dpp_add<0x143, 0xC>(v);
    return rlane(v, 63);
}
// per-half (32-lane) sum, broadcast to that half's lanes
__device__ __forceinline__ float half_sum(float v, bool hf) {
    v = dpp_add<0x111, 0xF>(v);
    v = dpp_add<0x112, 0xF>(v);
    v = dpp_add<0x114, 0xF>(v);
    v = dpp_add<0x118, 0xF>(v);
    v = dpp_add<0x142, 0xA>(v);   // lane31/lane63 hold the two half sums
    const float lo = rlane(v, 31);
    const float hi = rlane(v, 63);
    return hf ? hi : lo;
}

#if __has_builtin(__builtin_amdgcn_exp2f)
#define EXP2F(x) __builtin_amdgcn_exp2f(x)
#else
#define EXP2F(x) exp2f(x)
#endif
#if __has_builtin(__builtin_amdgcn_logf)
#define LOG2F(x) __builtin_amdgcn_logf(x)
#else
#define LOG2F(x) __log2f(x)
#endif

// r11: occupancy round. The alpha(e2)-convolution has NO feedback -> hoisted out of
// the serial loop into a per-wave PRE-PASS that materializes
//   F[c][j] = K*Gamma + sum_{m<32} K*alpha_m e2_{32c+j-m}
// in LDS. The serial loop's reset-at-consume reads F directly (exact regrouping of
// the validated FIR4 + incremental-ash + ginfE scheme; hand-rederived per lane).
// This removes the 32 pinned alpha regs + ring/FIR machinery from the serial loop:
// ~55-64 VGPR -> 8 waves/SIMD. 512-thread blocks, 8 segments (warm=1 chunk,
// decay-validated), 8192 waves = full 32/CU supply. Whh staging LDS is UNIONed
// with the F array (dead after the u-chain barrier).
__attribute__((amdgpu_flat_work_group_size(512, 512)))
__attribute__((amdgpu_waves_per_eu(4, 8)))
__global__ void garch_fused(
    const float* __restrict__ res,   // (B, S)
    const float* __restrict__ Wih,   // (64, 2)
    const float* __restrict__ bih,   // (64,)
    const float* __restrict__ Whh,   // (64, 64)
    const float* __restrict__ bhh,   // (64,)
    const float* __restrict__ fcw,   // (64,)
    const float* __restrict__ fcb,   // (1,)
    float* __restrict__ out)         // (B, S)
{
    // union: [0,4096) Whh stage (setup phase) -> [0,5120) F array (decode phase)
    __shared__ __align__(16) float smem[5120];
    __shared__ __align__(16) float ring[1024];   // 8 waves x 2 halves x 64 e2 ring
    __shared__ __align__(16) float ubuf[64];
    __shared__ float alpS[32], betS[32], gpreS[32], scS[4];

    const int tid  = threadIdx.x;
    const int lane = tid & 63;
    const int wv   = tid >> 6;
    const int l    = lane & 31;
    const bool hf  = (lane >= 32);

    const float Kc  = 1.44269504088896340736f;
    const float LN2 = 0.69314718055994530942f;

    // ---- cooperative stage Whh -> LDS ----
    {
        const f32x4* w4 = (const f32x4*)Whh;
        f32x4* wl4 = (f32x4*)smem;
        for (int i = tid; i < 1024; i += 512) wl4[i] = w4[i];
    }
    __syncthreads();

    const int rp = blockIdx.x;               // row pair
    const int p  = wv;                       // segment 0..7 (8 chunks each)
    const float* __restrict__ row  = res + (size_t)(2 * rp + (hf ? 1 : 0)) * S_LEN;
    float* __restrict__       orow = out + (size_t)(2 * rp + (hf ? 1 : 0)) * S_LEN;

    float* __restrict__ ringw = &ring[wv * 128 + (hf ? 64 : 0)];
    float* __restrict__ Fw    = smem + wv * 640 + (hf ? 32 : 0);  // F[ci] at +ci*64
    const int rotaddr = ((lane & 32) | ((l + 31) & 31)) << 2;

    // ======== pre-barrier prologue (no coefficients needed) ========
    float varh = 0.f, sigK = 0.f, carry = 0.f, ldn;
    int c0w, warm, nF;

    if (p == 0) {
        // sigma0 = var(row, ddof=1), per half — overlaps wave 7's u-chain
        float s1 = 0.f, s2 = 0.f;
#pragma unroll 8
        for (int i = 0; i < 64; ++i) {
            const float x = row[i * 32 + l];
            s1 += x;
            s2 = fmaf(x, x, s2);
        }
        s1 = half_sum(s1, hf);
        s2 = half_sum(s2, hf);
        const float mean = s1 * (1.0f / S_LEN);
        varh = (s2 - s1 * mean) * (1.0f / (S_LEN - 1));
        sigK = Kc * varh;
        carry = sigK;

        const float e0 = row[l];
        ringw[32 + l] = 0.f;         // chunk -1 = 0 (h0=0 start, exact)
        ringw[l] = e0 * e0;          // chunk 0 (slot 0)
        ldn = row[32 + l];           // raw chunk 1
        c0w = 0; warm = 0; nF = 9;
    } else {
        const int cw0 = 8 * p - 1;   // warm-up chunk
        const float eP = row[(cw0 - 1) * 32 + l];
        const float eC = row[cw0 * 32 + l];
        ringw[((cw0 - 1) & 1) * 32 + l] = eP * eP;
        ringw[(cw0 & 1) * 32 + l]       = eC * eC;
        ldn = row[(cw0 + 1) * 32 + l];
        c0w = cw0; warm = 1; nF = 10;
    }
    asm volatile("" ::: "memory");

    // ---- wave 7: u-chain + coefficient publish (LDS-sourced matvec) ----
    if (wv == 7) {
        const float w0l = Wih[lane * 2], w1l = Wih[lane * 2 + 1];
        const float blp = bih[lane] + bhh[lane];
        const float fl  = fcw[lane];

        const float A0  = Kc * wave_sum(fl * w0l);
        const float b0t = wave_sum(fl * w1l);
        const float Cg  = Kc * (wave_sum(fl * blp) + fcb[0]);
        if (lane == 0) { alpS[0] = A0; betS[0] = b0t; }
        float gpre_ = Cg, ginf_ = Cg;

        ubuf[lane] = fl;
        asm volatile("" ::: "memory");
        const f32x4* uq4 = (const f32x4*)ubuf;
        float u;
        {
            float n0 = 0.f, n1 = 0.f, n2 = 0.f, n3 = 0.f;
#pragma unroll 4
            for (int q = 0; q < 16; ++q) {
                const f32x4 uq = uq4[q];
                n0 = fmaf(smem[(4 * q + 0) * 64 + lane], uq.x, n0);
                n1 = fmaf(smem[(4 * q + 1) * 64 + lane], uq.y, n1);
                n2 = fmaf(smem[(4 * q + 2) * 64 + lane], uq.z, n2);
                n3 = fmaf(smem[(4 * q + 3) * 64 + lane], uq.w, n3);
            }
            u = (n0 + n1) + (n2 + n3);
        }
#pragma unroll 1
        for (int i = 1; i < 48; ++i) {
            const float daK = Kc * wave_sum(u * w0l);
            const float dbT = wave_sum(u * w1l);        // TRUE beta_i
            const float dgK = Kc * wave_sum(u * blp);   // K*g_{i-1}
            if (lane == 0 && i < 32) { alpS[i] = daK; betS[i] = dbT; }
            gpre_ += (lane >= i) ? dgK : 0.f;
            ginf_ += dgK;
            ubuf[lane] = u;
            asm volatile("" ::: "memory");
            float n0 = 0.f, n1 = 0.f, n2 = 0.f, n3 = 0.f;
#pragma unroll 4
            for (int q = 0; q < 16; ++q) {
                const f32x4 uq = uq4[q];
                n0 = fmaf(smem[(4 * q + 0) * 64 + lane], uq.x, n0);
                n1 = fmaf(smem[(4 * q + 1) * 64 + lane], uq.y, n1);
                n2 = fmaf(smem[(4 * q + 2) * 64 + lane], uq.z, n2);
                n3 = fmaf(smem[(4 * q + 3) * 64 + lane], uq.w, n3);
            }
            u = (n0 + n1) + (n2 + n3);
        }
        asm volatile("" ::: "memory");
        if (lane < 32) gpreS[lane] = gpre_;
        if (lane == 0) scS[0] = ginf_;
    }
    __syncthreads();     // Whh region now dead; smem becomes F

    // ======== uniforms to SGPRs; beta circulant to pinned regs ========
    const float ginf = rfl(scS[0]);
    const float bb0 = rfl(betS[0]), bb1 = rfl(betS[1]);
    const float bb2 = rfl(betS[2]), bb3 = rfl(betS[3]);

    f32x4 cb[8];
#pragma unroll
    for (int q = 0; q < 8; ++q) {
#pragma unroll
        for (int w = 0; w < 4; ++w) {
            const int m = (l - (4 * q + w)) & 31;
            cb[q][w] = (m < 4) ? 0.f : betS[m];
        }
    }
    asm("" : "+v"(cb[0]), "+v"(cb[1]), "+v"(cb[2]), "+v"(cb[3]),
             "+v"(cb[4]), "+v"(cb[5]), "+v"(cb[6]), "+v"(cb[7]));

    // ======== PRE-PASS: F[ci][l] for ci in [0,nF), latency-tolerant ========
    {
        const volatile float* aV = alpS;     // block coefficient caching into VGPRs
        int gc = c0w;
#pragma unroll 1
        for (int ci = 0; ci < nF; ++ci, ++gc) {
            const int s = gc & 1;
            const int a0 = (s << 5) + l;
            float Fv = (p == 0 && ci == 0) ? gpreS[l] : ginf;   // K*Gamma
#pragma unroll
            for (int m = 0; m < 32; ++m)
                Fv = fmaf(aV[m], ringw[(a0 - m) & 63], Fv);
            Fw[ci * 64 + l] = Fv;
            asm volatile("" ::: "memory");   // taps read before slot overwrite
            ringw[((s ^ 1) << 5) + l] = ldn * ldn;   // e2(gc+1)
            const int nc = (gc + 2 < 64) ? (gc + 2) : 63;
            ldn = row[nc * 32 + l];
            asm volatile("" ::: "memory");
        }
    }

    // ======== serial decode: chain = {fmaf, softplus}; reset reads F ========
    float acc = Fw[l];                       // F[c0][l] (+ zero sigma-history)
    float p1, p2, p3, vout = 0.f;
    {
        const float lo0 = rlane(acc, 0), hi0 = rlane(acc, 32);
        const float lo1 = rlane(acc, 1), hi1 = rlane(acc, 33);
        const float lo2 = rlane(acc, 2), hi2 = rlane(acc, 34);
        p1 = hf ? hi0 : lo0;
        p2 = hf ? hi1 : lo1;
        p3 = hf ? hi2 : lo2;
    }

    const int ncc = 8 + warm;
    const bool p0 = (p == 0);

#pragma unroll 1
    for (int cc = 0; cc < ncc; ++cc) {
        const int c = c0w + cc;
        const float sigchunk = carry;
        const float* Fn = Fw + (cc + 1) * 64;   // F[cc+1], per-half base

#pragma unroll
        for (int jg = 0; jg < 4; ++jg) {
            const f32x4 Fq0 = *(const f32x4*)(Fn + jg * 8);
            const f32x4 Fq1 = *(const f32x4*)(Fn + jg * 8 + 4);
#pragma unroll
            for (int k = 0; k < 8; ++k) {
                const int jj = (jg << 3) + k;
                const float bsh = cb[jj >> 2][jj & 3];    // pinned reg
                const float Fv = (k < 4) ? Fq0[k] : Fq1[k - 4];  // half-uniform
                const float xp = fmaf(bb0, sigK, p1);     // on-chain
                acc = fmaf(bsh, sigK, acc);               // sigma lags >=4 (wrap)
                const bool mine = (l == jj);
                acc = mine ? Fv : acc;                    // reset = F[cc+1][jj]
                const float tlo = rlane(acc, (jj + 3) & 31);
                const float thi = rlane(acc, 32 + ((jj + 3) & 31));
                const float t = hf ? thi : tlo;           // hoisted-3 read, per half
                p1 = fmaf(bb1, sigK, p2);
                p2 = fmaf(bb2, sigK, p3);
                p3 = fmaf(bb3, sigK, t);
                const float ee = EXP2F(-__builtin_fabsf(xp));
                sigK = fmaxf(xp, 0.f) + LOG2F(1.0f + ee); // K-domain softplus
                vout = mine ? sigK : vout;                // lane jj: sigma_{32c+jj+1}
            }
        }

        if (cc >= warm) {
            const float rotv = __int_as_float(
                __builtin_amdgcn_ds_bpermute(rotaddr, __float_as_int(vout)));
            const float sv = (l == 0) ? sigchunk : rotv;
            float outv = fmaf(sv, LN2, 1e-6f);
            if (p0 && cc == 0) outv = (l == 0) ? varh : outv;   // t=0: exact variance
            orow[(c << 5) + l] = outv;
        }
        {
            const float c1v = rlane(vout, 31);
            const float c2v = rlane(vout, 63);
            carry = hf ? c2v : c1v;
        }
    }
}

extern "C" void kernel_launch(void* const* d_in, const int* in_sizes, int n_in,
                              void* d_out, int out_size, void* d_ws, size_t ws_size,
                              hipStream_t stream) {
    const float* res = (const float*)d_in[0];
    const float* Wih = (const float*)d_in[1];
    const float* bih = (const float*)d_in[2];
    const float* Whh = (const float*)d_in[3];
    const float* bhh = (const float*)d_in[4];
    const float* fcw = (const float*)d_in[5];
    const float* fcb = (const float*)d_in[6];
    float* out = (float*)d_out;

    hipLaunchKernelGGL(garch_fused, dim3(1024), dim3(512), 0, stream,
                       res, Wih, bih, Whh, bhh, fcw, fcb, out);
}